// Round 7
// baseline (360.397 us; speedup 1.0000x reference)
//
#include <hip/hip_runtime.h>
#include <hip/hip_bf16.h>

// Problem constants (M is a static constant in the reference; N,E derived from in_sizes)
#define D 128
#define MSEG 10000
#define FILL_CHB 128   // E-chunks per partition in the fill work queue

typedef __attribute__((ext_vector_type(8))) __bf16 bf16x8;
typedef __attribute__((ext_vector_type(2))) __bf16 bf16x2;
typedef __attribute__((ext_vector_type(4))) float f32x4;

// NOTE: the reference's `col - min(col)` is a pure relabeling of segment ids.
// e_feat/e_proj are produced and consumed through the same id map, so the output
// is invariant — we skip the min entirely (col values are already in [0, M)).

// ---------------- histogram ----------------
__global__ void hist_kernel(const int* __restrict__ row, const int* __restrict__ col, int n,
                            int* __restrict__ ccnt, int* __restrict__ rcnt) {
    int i = blockIdx.x * blockDim.x + threadIdx.x;
    if (i >= n) return;
    atomicAdd(&ccnt[col[i]], 1);
    atomicAdd(&rcnt[row[i]], 1);
}

// ---------------- W pre-convert: f32 -> bf16 planes in LDS layout ----------------
// wp layout: [Wv 16 planes | We 16 planes | Wu 32 planes], plane = 128 cols x 8 k,
// element (p,c,j) at ((p*128)+c)*8+j  ==  W[p*8+j][c].
__global__ __launch_bounds__(256) void prep_w(const float* __restrict__ Wv, const float* __restrict__ We,
                                              const float* __restrict__ Wu, __bf16* __restrict__ wp) {
    int idx = blockIdx.x * 256 + threadIdx.x;   // (p_global, c): 64*128 = 8192
    if (idx >= 8192) return;
    int pg = idx >> 7;
    int c = idx & 127;
    const float* src; int pl;
    if (pg < 16)      { src = Wv; pl = pg; }
    else if (pg < 32) { src = We; pl = pg - 16; }
    else              { src = Wu; pl = pg - 32; }
    union { bf16x8 v; __bf16 e[8]; } u;
    #pragma unroll
    for (int j = 0; j < 8; ++j) u.e[j] = (__bf16)src[(pl * 8 + j) * 128 + c];
    *(bf16x8*)&wp[(size_t)idx * 8] = u.v;
}

// ---------------- hierarchical scan, phase 1: per-block local scan + partial ----------------
__global__ __launch_bounds__(1024) void scan_p1(const int* __restrict__ cntA, int* __restrict__ offA, int nA,
                                                const int* __restrict__ cntB, int* __restrict__ offB, int nB,
                                                int bA, int* __restrict__ partials) {
    __shared__ int wsum[16];
    __shared__ int stotal;
    int b = blockIdx.x;
    const int* cnt; int* off; int n; int cb;
    if (b < bA) { cnt = cntA; off = offA; n = nA; cb = b; }
    else        { cnt = cntB; off = offB; n = nB; cb = b - bA; }
    int tid = threadIdx.x, lane = tid & 63, wid = tid >> 6;
    int idx = cb * 4096 + tid * 4;

    int4 v = make_int4(0, 0, 0, 0);
    if (idx + 3 < n) v = *(const int4*)&cnt[idx];
    else {
        if (idx     < n) v.x = cnt[idx];
        if (idx + 1 < n) v.y = cnt[idx + 1];
        if (idx + 2 < n) v.z = cnt[idx + 2];
        if (idx + 3 < n) v.w = cnt[idx + 3];
    }
    int e1 = v.x, e2 = e1 + v.y, e3 = e2 + v.z, ts = e3 + v.w;
    int incl = ts;
    #pragma unroll
    for (int o = 1; o < 64; o <<= 1) { int t = __shfl_up(incl, o, 64); if (lane >= o) incl += t; }
    if (lane == 63) wsum[wid] = incl;
    int wexcl = incl - ts;
    __syncthreads();
    if (wid == 0) {
        int wv = (lane < 16) ? wsum[lane] : 0;
        int wi = wv;
        #pragma unroll
        for (int o = 1; o < 16; o <<= 1) { int t = __shfl_up(wi, o, 64); if (lane >= o) wi += t; }
        if (lane < 16) wsum[lane] = wi - wv;
        if (lane == 15) stotal = wi;
    }
    __syncthreads();
    int tb = wsum[wid] + wexcl;
    if (idx + 3 < n) *(int4*)&off[idx] = make_int4(tb, tb + e1, tb + e2, tb + e3);
    else {
        if (idx     < n) off[idx]     = tb;
        if (idx + 1 < n) off[idx + 1] = tb + e1;
        if (idx + 2 < n) off[idx + 2] = tb + e2;
        if (idx + 3 < n) off[idx + 3] = tb + e3;
    }
    if (tid == 0) partials[b] = stotal;
}

// ---------------- hierarchical scan, phase 2: add block base, write off+cur+tail ------------
__global__ __launch_bounds__(1024) void scan_p2(int* __restrict__ offA, int* __restrict__ curA, int nA,
                                                int* __restrict__ offB, int* __restrict__ curB, int nB,
                                                int bA, int nblk, const int* __restrict__ partials) {
    __shared__ int sp[32];
    int b = blockIdx.x;
    int tid = threadIdx.x;
    if (tid < nblk) sp[tid] = partials[tid];
    __syncthreads();
    int* off; int* cur; int n; int cb; int first;
    if (b < bA) { off = offA; cur = curA; n = nA; cb = b;      first = 0; }
    else        { off = offB; cur = curB; n = nB; cb = b - bA; first = bA; }
    int basev = 0;
    for (int j = first; j < first + cb; ++j) basev += sp[j];
    int idx = cb * 4096 + tid * 4;
    if (idx + 3 < n) {
        int4 v = *(const int4*)&off[idx];
        v.x += basev; v.y += basev; v.z += basev; v.w += basev;
        *(int4*)&off[idx] = v;
        *(int4*)&cur[idx] = v;
    } else {
        #pragma unroll
        for (int j = 0; j < 4; ++j)
            if (idx + j < n) { int t = off[idx + j] + basev; off[idx + j] = t; cur[idx + j] = t; }
    }
    bool last = (b == bA - 1) || (b == nblk - 1);
    if (last && tid == 0) off[n] = basev + sp[first + cb];
}

// ---------------- fill CSR lists: XCD-guided work queue ----------------
// 8 destination partitions x FILL_CHB E-chunks = work items. A block reads its REAL
// XCD id (HW_REG_XCC_ID, simm16 = 20 | (0<<6) | (3<<11) = 6164) and pops items from
// that partition's queue first (steals from neighbors when drained). Partition p's
// clist/rlist lines are then written (almost) only from XCD p's L2 -> no cross-XCD
// partial-line writeback amplification (R6: WRITE_SIZE 37MB for ~4MB of lists; the
// static blockIdx&7 heuristic did NOT match the real XCD mapping). Exactly-once by
// atomic ticket pop; all items drained by stealing -> correctness is mapping-independent.
__global__ __launch_bounds__(256) void fill_kernel(const int* __restrict__ row, const int* __restrict__ col,
                                                   int n, int* __restrict__ ccur, int* __restrict__ rcur,
                                                   int* __restrict__ clist, int* __restrict__ rlist,
                                                   int M, int N, int* __restrict__ qcnt) {
    __shared__ int s_item;
    int xcd = __builtin_amdgcn_s_getreg(6164) & 7;   // HW_REG_XCC_ID[3:0]
    int tid = threadIdx.x;
    int cs = (n + FILL_CHB - 1) / FILL_CHB;
    for (;;) {
        __syncthreads();                 // prior iteration's s_item reads done
        if (tid == 0) {
            int it = -1;
            for (int t = 0; t < 8; ++t) {
                int q = (xcd + t) & 7;
                int k = atomicAdd(&qcnt[q], 1);
                if (k < FILL_CHB) { it = q * FILL_CHB + k; break; }
            }
            s_item = it;
        }
        __syncthreads();
        int item = s_item;
        if (item < 0) break;
        int part = item / FILL_CHB;
        int chunk = item % FILL_CHB;
        int clo = part * (M >> 3), chi = clo + (M >> 3);          // M divisible by 8
        int rchunk = (N + 7) >> 3;
        int rlo = part * rchunk, rhi = min(N, rlo + rchunk);
        int i0 = chunk * cs, i1 = min(n, i0 + cs);
        for (int i = i0 + tid; i < i1; i += 256) {
            int c = col[i], r = row[i];
            if (c >= clo && c < chi) clist[atomicAdd(&ccur[c], 1)] = r;
            if (r >= rlo && r < rhi) rlist[atomicAdd(&rcur[r], 1)] = c;
        }
    }
}

// ---------------- MFMA bf16 GEMM: C[rows x 128] = act( concat(A0[,A1]) @ W + b ) -------------
// W comes pre-converted (prep_w) in the exact LDS plane layout -> staging is a straight
// 16B-copy (half the bytes of f32, no convert ALU).
template<int NCHUNK, bool ABF16, bool FINAL>
__global__ __launch_bounds__(256) void gemm_mfma(const void* __restrict__ A0v,
                                                 const void* __restrict__ A1v,
                                                 const __bf16* __restrict__ Wp,
                                                 const float* __restrict__ bias,
                                                 void* __restrict__ Cv, int rows) {
    __shared__ __bf16 Ws[NCHUNK * 16 * 128 * 8];   // 32KB (NCHUNK=1) / 64KB (NCHUNK=2)
    __shared__ __bf16 As[2][4 * 128 * 8];          // 2 x 8KB
    int tid = threadIdx.x;
    int w = tid >> 6, lane = tid & 63;
    int quad = lane >> 4, l15 = lane & 15;
    int r0 = blockIdx.x * 128;
    int mh = (w >> 1) * 64, nh = (w & 1) * 64;

    // ---- stage W planes (bf16 -> bf16 memcpy)
    {
        const bf16x8* Wp8 = (const bf16x8*)Wp;
        #pragma unroll
        for (int it = 0; it < NCHUNK * 8; ++it) {
            int idx = it * 256 + tid;              // bf16x8 units
            *(bf16x8*)&Ws[(size_t)idx * 8] = Wp8[idx];
        }
    }

    f32x4 acc[4][4];
    {
        f32x4 z = {0.f, 0.f, 0.f, 0.f};
        #pragma unroll
        for (int i = 0; i < 4; ++i)
            #pragma unroll
            for (int j = 0; j < 4; ++j) acc[i][j] = z;
    }

    auto stageA = [&](int t, int b) {
        int src = t >> 2;
        int k0 = (t & 3) * 32;
        #pragma unroll
        for (int h = 0; h < 2; ++h) {
            int i = h * 256 + tid;                // 0..511 entry (q,r)
            int q = i >> 7, r = i & 127;
            int rr = min(r0 + r, rows - 1);
            if (ABF16) {
                const __bf16* Ap = (const __bf16*)(src ? A1v : A0v) + (size_t)rr * D + k0 + q * 8;
                *(bf16x8*)&As[b][i * 8] = *(const bf16x8*)Ap;
            } else {
                const float* Ap = (const float*)A0v + (size_t)rr * D + k0 + q * 8;
                float4 f0 = *(const float4*)Ap;
                float4 f1 = *(const float4*)(Ap + 4);
                union { bf16x8 v; __bf16 e[8]; } u;
                u.e[0] = (__bf16)f0.x; u.e[1] = (__bf16)f0.y; u.e[2] = (__bf16)f0.z; u.e[3] = (__bf16)f0.w;
                u.e[4] = (__bf16)f1.x; u.e[5] = (__bf16)f1.y; u.e[6] = (__bf16)f1.z; u.e[7] = (__bf16)f1.w;
                *(bf16x8*)&As[b][i * 8] = u.v;
            }
        }
    };

    stageA(0, 0);
    const int T = NCHUNK * 4;
    for (int t = 0; t < T; ++t) {
        __syncthreads();                          // chunk t staged; prev reads of buf (t+1)&1 done
        if (t + 1 < T) stageA(t + 1, (t + 1) & 1);
        int b = t & 1;
        bf16x8 af[4], bfr[4];
        #pragma unroll
        for (int mi = 0; mi < 4; ++mi)
            af[mi] = *(const bf16x8*)&As[b][(quad * 128 + mh + mi * 16 + l15) * 8];
        #pragma unroll
        for (int ni = 0; ni < 4; ++ni)
            bfr[ni] = *(const bf16x8*)&Ws[((t * 4 + quad) * 128 + nh + ni * 16 + l15) * 8];
        #pragma unroll
        for (int mi = 0; mi < 4; ++mi)
            #pragma unroll
            for (int ni = 0; ni < 4; ++ni)
                acc[mi][ni] = __builtin_amdgcn_mfma_f32_16x16x32_bf16(af[mi], bfr[ni], acc[mi][ni], 0, 0, 0);
    }

    // ---- epilogue: C/D layout col=lane&15, row=quad*4+reg
    __bf16* Cb = (__bf16*)Cv;
    float* Cf = (float*)Cv;
    #pragma unroll
    for (int ni = 0; ni < 4; ++ni) {
        int colc = nh + ni * 16 + l15;
        float bv = FINAL ? bias[colc] : 0.f;
        #pragma unroll
        for (int mi = 0; mi < 4; ++mi) {
            #pragma unroll
            for (int v = 0; v < 4; ++v) {
                int r = r0 + mh + mi * 16 + quad * 4 + v;
                if (r < rows) {
                    float val = acc[mi][ni][v];
                    if (FINAL) Cf[(size_t)r * D + colc] = fmaxf(val + bv, 0.f);
                    else       Cb[(size_t)r * D + colc] = (__bf16)val;
                }
            }
        }
    }
}

// ---------------- segment mean via CSR: one wave = 4 row slots x 16 lanes ----------------
__global__ __launch_bounds__(256) void agg_mean(const __bf16* __restrict__ src, const int* __restrict__ off,
                                                const int* __restrict__ list, __bf16* __restrict__ dst,
                                                int nseg) {
    int seg = blockIdx.x * 4 + (threadIdx.x >> 6);
    if (seg >= nseg) return;
    int lane = threadIdx.x & 63;
    int slot = lane >> 4, cg = lane & 15;
    int s = off[seg], e = off[seg + 1];
    int cnt = e - s;
    float acc[8];
    #pragma unroll
    for (int j = 0; j < 8; ++j) acc[j] = 0.f;

    int i = s;
    for (; i + 8 <= e; i += 8) {
        int r0 = list[i + slot];
        int r1 = list[i + 4 + slot];
        bf16x8 v0 = *(const bf16x8*)&src[(size_t)r0 * D + cg * 8];
        bf16x8 v1 = *(const bf16x8*)&src[(size_t)r1 * D + cg * 8];
        #pragma unroll
        for (int j = 0; j < 8; ++j) acc[j] += (float)v0[j] + (float)v1[j];
    }
    for (; i < e; i += 4) {
        int ii = i + slot;
        if (ii < e) {
            int r = list[ii];
            bf16x8 v = *(const bf16x8*)&src[(size_t)r * D + cg * 8];
            #pragma unroll
            for (int j = 0; j < 8; ++j) acc[j] += (float)v[j];
        }
    }
    #pragma unroll
    for (int j = 0; j < 8; ++j) {
        acc[j] += __shfl_xor(acc[j], 16, 64);
        acc[j] += __shfl_xor(acc[j], 32, 64);
    }
    if (slot == 0) {
        float inv = 1.f / (float)max(cnt, 1);
        union { bf16x8 v; __bf16 e[8]; } u;
        #pragma unroll
        for (int j = 0; j < 8; ++j) u.e[j] = (__bf16)(acc[j] * inv);
        *(bf16x8*)&dst[(size_t)seg * D + cg * 8] = u.v;
    }
}

extern "C" void kernel_launch(void* const* d_in, const int* in_sizes, int n_in,
                              void* d_out, int out_size, void* d_ws, size_t ws_size,
                              hipStream_t stream) {
    const float* x  = (const float*)d_in[0];
    const int*   ei = (const int*)d_in[1];
    const float* Wv = (const float*)d_in[2];
    const float* We = (const float*)d_in[3];
    const float* Wu = (const float*)d_in[4];
    const float* bu = (const float*)d_in[5];
    float* out = (float*)d_out;

    const int N = in_sizes[0] / D;       // 50000
    const int E = in_sizes[1] / 2;       // 500000
    const int M = MSEG;                  // 10000 (static in reference)
    const int* row = ei;
    const int* col = ei + E;

    // workspace carve-out (256B aligned)
    char* p = (char*)d_ws;
    auto alloc = [&](size_t bytes) { char* q = p; p += (bytes + 255) & ~(size_t)255; return q; };
    __bf16* xp     = (__bf16*)alloc((size_t)N * D * 2);
    __bf16* e_feat = (__bf16*)alloc((size_t)M * D * 2);
    __bf16* e_proj = (__bf16*)alloc((size_t)M * D * 2);
    __bf16* n_agg  = (__bf16*)alloc((size_t)N * D * 2);
    __bf16* wp     = (__bf16*)alloc((size_t)64 * 128 * 8 * 2);   // 128KB plane-layout W
    int* ccnt  = (int*)alloc((size_t)M * 4);
    int* coff  = (int*)alloc((size_t)(M + 1) * 4);
    int* ccur  = (int*)alloc((size_t)M * 4);
    int* rcnt  = (int*)alloc((size_t)N * 4);
    int* roff  = (int*)alloc((size_t)(N + 1) * 4);
    int* rcur  = (int*)alloc((size_t)N * 4);
    int* clist = (int*)alloc((size_t)E * 4);
    int* rlist = (int*)alloc((size_t)E * 4);
    int* partials = (int*)alloc(256);
    int* qcnt     = (int*)alloc(256);

    hipMemsetAsync(ccnt, 0, (size_t)M * 4, stream);
    hipMemsetAsync(rcnt, 0, (size_t)N * 4, stream);
    hipMemsetAsync(qcnt, 0, 32, stream);

    const int bA = (M + 4095) / 4096;    // 3
    const int bB = (N + 4095) / 4096;    // 13
    const int nblk = bA + bB;            // 16

    int eb = (E + 255) / 256;
    prep_w<<<32, 256, 0, stream>>>(Wv, We, Wu, wp);
    hist_kernel<<<eb, 256, 0, stream>>>(row, col, E, ccnt, rcnt);
    scan_p1<<<nblk, 1024, 0, stream>>>(ccnt, coff, M, rcnt, roff, N, bA, partials);
    scan_p2<<<nblk, 1024, 0, stream>>>(coff, ccur, M, roff, rcur, N, bA, nblk, partials);
    fill_kernel<<<1024, 256, 0, stream>>>(row, col, E, ccur, rcur, clist, rlist, M, N, qcnt);

    // x_proj (bf16) = x @ Wv
    gemm_mfma<1, false, false><<<(N + 127) / 128, 256, 0, stream>>>(x, nullptr, wp, nullptr, xp, N);
    agg_mean<<<(M + 3) / 4, 256, 0, stream>>>(xp, coff, clist, e_feat, M);
    gemm_mfma<1, true, false><<<(M + 127) / 128, 256, 0, stream>>>(e_feat, nullptr, wp + 16384, nullptr, e_proj, M);
    agg_mean<<<(N + 3) / 4, 256, 0, stream>>>(e_proj, roff, rlist, n_agg, N);
    gemm_mfma<2, true, true><<<(N + 127) / 128, 256, 0, stream>>>(xp, n_agg, wp + 32768, bu, out, N);
}